// Round 7
// baseline (692.914 us; speedup 1.0000x reference)
//
#include <hip/hip_runtime.h>
#include <hip/hip_fp16.h>
#include <cstdint>
#include <cstddef>

// Problem constants (fixed by the reference)
static constexpr int NN = 100000;   // nodes
static constexpr int NE = 3200000;  // edges
static constexpr int NG = 256;      // graphs
static constexpr int NBK = (NN + 127) / 128;  // dst/src buckets of 128 nodes = 782
static constexpr int EPB = NE / 256;          // edges per hist/scatter block = 12500
static constexpr int GB_BATCH = (NN + 255) / 256;                    // 391
static constexpr int GB_PREPW = (192 * 128 + 192 * 64 + 255) / 256;  // 144
static constexpr int GB_HIST = 256;

typedef _Float16 h8 __attribute__((ext_vector_type(8)));
typedef float f4v __attribute__((ext_vector_type(4)));

__device__ __forceinline__ void atomAddF(float* p, float v) {
  unsafeAtomicAdd(p, v);  // native global_atomic_add_f32 on gfx950
}
__device__ __forceinline__ float h2f(__half h) { return __half2float(h); }

// ---------------------------------------------------------------------------
// dtype hedge: reference says int64, harness doc says int32. Detect at runtime.
__global__ void k_detect(const int* __restrict__ ei, int* __restrict__ flag) {
  if (threadIdx.x == 0 && blockIdx.x == 0) {
    int nz = 0;
    for (int i = 0; i < 64; ++i) nz += (ei[2 * i + 1] != 0) ? 1 : 0;
    *flag = (nz == 0) ? 1 : 0;  // 1 => int64 layout
  }
}

__device__ __forceinline__ int ld_idx(const void* raw, int f, int i) {
  return f ? (int)((const long long*)raw)[i] : ((const int*)raw)[i];
}

// ---------------------------------------------------------------------------
// Front kernel: blockIdx ranges -> [batch repack+gcnt | weight prep | edge hist]
__global__ __launch_bounds__(256) void k_front(const void* __restrict__ bat,
                                               const void* __restrict__ ei,
                                               const int* __restrict__ flag,
                                               const float* __restrict__ W1,
                                               const float* __restrict__ W2,
                                               int* __restrict__ b32,
                                               int* __restrict__ gcnt,
                                               __half* __restrict__ BtX,
                                               __half* __restrict__ BtH2,
                                               int* __restrict__ sCnt,
                                               int* __restrict__ dCnt,
                                               int* __restrict__ hsBlk,
                                               int* __restrict__ hdBlk) {
  __shared__ int sh[2 * NBK];
  int b = blockIdx.x;
  int t = threadIdx.x;
  if (b < GB_BATCH) {
    // ---- batch repack + graph counts (batch sorted -> per-block runs)
    int* cnt = sh;
    cnt[t] = 0;
    int blk0 = b * 256;
    int f = *flag;
    int g0 = ld_idx(bat, f, blk0);
    __syncthreads();
    int i = blk0 + t;
    if (i < NN) {
      int g = ld_idx(bat, f, i);
      b32[i] = g;
      atomicAdd(&cnt[g - g0], 1);
    }
    __syncthreads();
    if (cnt[t] > 0) atomicAdd(&gcnt[g0 + t], cnt[t]);
  } else if (b < GB_BATCH + GB_PREPW) {
    // ---- weight prep:
    // BtX[192][128]: rows 0-63 = (W1_0-W1_2)^T, 64-127 = W1_1^T, 128-191 = W1_2^T
    // BtH2[192][64]: rows 0-63 = (W2_0-W2_2)^T, 64-127 = W2_1^T, 128-191 = W2_2^T
    int u = (b - GB_BATCH) * 256 + t;
    if (u < 192 * 128) {
      int n = u >> 7, k = u & 127;
      float v;
      if (n < 64)       v = W1[k * 64 + n] - W1[16384 + k * 64 + n];
      else if (n < 128) v = W1[8192 + k * 64 + (n - 64)];
      else              v = W1[16384 + k * 64 + (n - 128)];
      BtX[n * 128 + k] = __float2half_rn(v);
    } else if (u < 192 * 128 + 192 * 64) {
      int u2 = u - 192 * 128;
      int n = u2 >> 6, k = u2 & 63;
      float v;
      if (n < 64)       v = W2[k * 64 + n] - W2[8192 + k * 64 + n];
      else if (n < 128) v = W2[4096 + k * 64 + (n - 64)];
      else              v = W2[8192 + k * 64 + (n - 128)];
      BtH2[n * 64 + k] = __float2half_rn(v);
    }
  } else {
    // ---- edge histogram (per-block hists persisted for k_scatter)
    int hb = b - GB_BATCH - GB_PREPW;
    int* hs = sh;
    int* hd = sh + NBK;
    for (int i = t; i < NBK; i += 256) { hs[i] = 0; hd[i] = 0; }
    __syncthreads();
    int f = *flag;
    int e0 = hb * EPB;
    for (int e = e0 + t; e < e0 + EPB; e += 256) {
      int s = ld_idx(ei, f, e);
      int d = ld_idx(ei, f, NE + e);
      atomicAdd(&hs[s >> 7], 1);
      atomicAdd(&hd[d >> 7], 1);
    }
    __syncthreads();
    size_t hoff = (size_t)hb * NBK;
    for (int i = t; i < NBK; i += 256) {
      int a = hs[i], c = hd[i];
      hsBlk[hoff + i] = a;
      hdBlk[hoff + i] = c;
      if (a) atomicAdd(&sCnt[i], a);
      if (c) atomicAdd(&dCnt[i], c);
    }
  }
}

// Exclusive scan of both bucket-count arrays (782 <= 1024, one block).
__global__ __launch_bounds__(1024) void k_scan(const int* __restrict__ sCnt,
                                               const int* __restrict__ dCnt,
                                               int* __restrict__ sBase,
                                               int* __restrict__ dBase,
                                               int* __restrict__ sCur,
                                               int* __restrict__ dCur) {
  __shared__ int sh1[1024], sh2[1024];
  int t = threadIdx.x;
  int v1 = (t < NBK) ? sCnt[t] : 0;
  int v2 = (t < NBK) ? dCnt[t] : 0;
  sh1[t] = v1; sh2[t] = v2;
  __syncthreads();
  for (int off = 1; off < 1024; off <<= 1) {
    int a1 = (t >= off) ? sh1[t - off] : 0;
    int a2 = (t >= off) ? sh2[t - off] : 0;
    __syncthreads();
    sh1[t] += a1; sh2[t] += a2;
    __syncthreads();
  }
  if (t <= NBK) {
    int b1 = sh1[t] - v1, b2 = sh2[t] - v2;  // exclusive
    sBase[t] = b1; dBase[t] = b2;
    if (t < NBK) { sCur[t] = b1; dCur[t] = b2; }
  }
}

// Pass 2: chunk-reserve per (block,bucket) using saved per-block hists,
// scatter src ids (by src bucket) and packed (src | dst_local<<17) records.
__global__ __launch_bounds__(256) void k_scatter(const void* __restrict__ raw,
                                                 const int* __restrict__ flag,
                                                 const int* __restrict__ hsBlk,
                                                 const int* __restrict__ hdBlk,
                                                 int* __restrict__ sCur,
                                                 int* __restrict__ dCur,
                                                 int* __restrict__ srclist,
                                                 unsigned* __restrict__ elist) {
  __shared__ int hs[NBK], hd[NBK], cbS[NBK], cbD[NBK];
  int t = threadIdx.x;
  size_t hb = (size_t)blockIdx.x * NBK;
  for (int i = t; i < NBK; i += 256) {
    int c1 = hsBlk[hb + i];
    cbS[i] = c1 ? atomicAdd(&sCur[i], c1) : 0;
    int c2 = hdBlk[hb + i];
    cbD[i] = c2 ? atomicAdd(&dCur[i], c2) : 0;
    hs[i] = 0; hd[i] = 0;
  }
  __syncthreads();
  int f = *flag;
  int e0 = blockIdx.x * EPB;
  for (int e = e0 + t; e < e0 + EPB; e += 256) {
    int s = ld_idx(raw, f, e);
    int d = ld_idx(raw, f, NE + e);
    int bs = s >> 7, bd = d >> 7;
    int ls = atomicAdd(&hs[bs], 1);
    int ld2 = atomicAdd(&hd[bd], 1);
    srclist[cbS[bs] + ls] = s;
    elist[cbD[bd] + ld2] = (unsigned)s | ((unsigned)(d & 127) << 17);
  }
}

// Back kernel: [out-degree -> dinv | per-bucket counting sort -> CSR]
// adj is a distinct buffer (no aliasing with srclist: blocks run concurrently).
__global__ __launch_bounds__(256) void k_back(const int* __restrict__ sBase,
                                              const int* __restrict__ srclist,
                                              float* __restrict__ dinv,
                                              const int* __restrict__ dBase,
                                              const unsigned* __restrict__ elist,
                                              int* __restrict__ rowptr,
                                              int* __restrict__ adj) {
  __shared__ int cnt[128], sc[128], off[128], fill[128];
  int t = threadIdx.x;
  int bb = blockIdx.x;
  if (bb < NBK) {
    int b = bb;
    if (t < 128) cnt[t] = 0;
    __syncthreads();
    int e0 = sBase[b], e1 = sBase[b + 1];
    for (int i = e0 + t; i < e1; i += 256) atomicAdd(&cnt[srclist[i] & 127], 1);
    __syncthreads();
    if (t < 128) {
      int node = b * 128 + t;
      if (node < NN) {
        int c = cnt[t];
        dinv[node] = (c > 0) ? rsqrtf((float)c) : 0.f;
      }
    }
  } else {
    int b = bb - NBK;
    if (t < 128) { cnt[t] = 0; fill[t] = 0; }
    __syncthreads();
    int e0 = dBase[b], e1 = dBase[b + 1];
    for (int i = e0 + t; i < e1; i += 256) atomicAdd(&cnt[elist[i] >> 17], 1);
    __syncthreads();
    if (t < 128) sc[t] = cnt[t];
    __syncthreads();
    for (int o = 1; o < 128; o <<= 1) {
      int a = (t < 128 && t >= o) ? sc[t - o] : 0;
      __syncthreads();
      if (t < 128) sc[t] += a;
      __syncthreads();
    }
    if (t < 128) {
      off[t] = sc[t] - cnt[t];  // exclusive
      int node = b * 128 + t;
      if (node < NN) rowptr[node] = e0 + off[t];
    }
    if (b == NBK - 1 && t == 0) rowptr[NN] = e1;
    __syncthreads();
    for (int i = e0 + t; i < e1; i += 256) {
      unsigned w2 = elist[i];
      int l = (int)(w2 >> 17);
      int pos = atomicAdd(&fill[l], 1);
      adj[e0 + off[l] + pos] = (int)(w2 & 0x1FFFFu);
    }
  }
}

// ---------------------------------------------------------------------------
// MFMA GEMM X: [128 nodes] x [K=128] x [N=192].
// Outputs (all fp16, row-major 64): gV0 = x@(W1_0-W1_2), gA1 = x@W1_1,
// gU2s = dinv .* (x@W1_2)   (only gU2s is gathered later).
static constexpr int AW = 136;  // LDS row stride (halves)
__global__ __launch_bounds__(256) void k_gemm_x(const float* __restrict__ x,
                                                const __half* __restrict__ BtX,
                                                const float* __restrict__ dinv,
                                                __half* __restrict__ gV0,
                                                __half* __restrict__ gA1,
                                                __half* __restrict__ gU2s) {
  __shared__ __align__(16) _Float16 As[128 * AW];
  const int t = threadIdx.x;
  const int n0 = blockIdx.x * 128;
  {
    int i = t >> 1, q = t & 1;
    int row = n0 + i;
    _Float16* dst = As + i * AW + q * 64;
    if (row < NN) {
      const float* src = x + (size_t)row * 128 + q * 64;
#pragma unroll
      for (int c = 0; c < 64; c += 4) {
        float4 v = *reinterpret_cast<const float4*>(src + c);
        ushort4 u;
        u.x = __half_as_ushort(__float2half_rn(v.x));
        u.y = __half_as_ushort(__float2half_rn(v.y));
        u.z = __half_as_ushort(__float2half_rn(v.z));
        u.w = __half_as_ushort(__float2half_rn(v.w));
        *reinterpret_cast<ushort4*>(dst + c) = u;
      }
    } else {
#pragma unroll
      for (int c = 0; c < 64; c += 4)
        *reinterpret_cast<ushort4*>(dst + c) = make_ushort4(0, 0, 0, 0);
    }
  }
  __syncthreads();
  const int w = t >> 6, lane = t & 63;
  const int quad = lane >> 4, l = lane & 15;
  f4v acc[2][12];
#pragma unroll
  for (int mt = 0; mt < 2; ++mt)
#pragma unroll
    for (int nt = 0; nt < 12; ++nt) acc[mt][nt] = (f4v){0.f, 0.f, 0.f, 0.f};

#pragma unroll
  for (int ks = 0; ks < 4; ++ks) {
    int k0 = ks * 32 + quad * 8;
    h8 a0 = *reinterpret_cast<const h8*>(As + (w * 32 + l) * AW + k0);
    h8 a1 = *reinterpret_cast<const h8*>(As + (w * 32 + 16 + l) * AW + k0);
#pragma unroll
    for (int nt = 0; nt < 12; ++nt) {
      h8 b = *reinterpret_cast<const h8*>(BtX + (size_t)(nt * 16 + l) * 128 + k0);
      acc[0][nt] = __builtin_amdgcn_mfma_f32_16x16x32_f16(a0, b, acc[0][nt], 0, 0, 0);
      acc[1][nt] = __builtin_amdgcn_mfma_f32_16x16x32_f16(a1, b, acc[1][nt], 0, 0, 0);
    }
  }
#pragma unroll
  for (int mt = 0; mt < 2; ++mt) {
#pragma unroll
    for (int r = 0; r < 4; ++r) {
      int row = n0 + w * 32 + mt * 16 + quad * 4 + r;
      if (row < NN) {
        float dv = dinv[row];
#pragma unroll
        for (int nt2 = 0; nt2 < 4; ++nt2) {
          int col = nt2 * 16 + l;
          gV0[(size_t)row * 64 + col] = __float2half_rn(acc[mt][nt2][r]);
          gA1[(size_t)row * 64 + col] = __float2half_rn(acc[mt][4 + nt2][r]);
          gU2s[(size_t)row * 64 + col] = __float2half_rn(dv * acc[mt][8 + nt2][r]);
        }
      }
    }
  }
}

// ---------------------------------------------------------------------------
// MFMA GEMM H: [128 nodes] x [K=64] x [N=192] on h1.
// Outputs: gV02 = h1@(W2_0-W2_2), gA2 = h1@W2_1, gB2s = dinv .* (h1@W2_2).
static constexpr int HW2 = 72;  // LDS row stride (halves)
__global__ __launch_bounds__(256) void k_gemm_h(const __half* __restrict__ gH1,
                                                const __half* __restrict__ BtH2,
                                                const float* __restrict__ dinv,
                                                __half* __restrict__ gV02,
                                                __half* __restrict__ gA2,
                                                __half* __restrict__ gB2s) {
  __shared__ __align__(16) _Float16 As[128 * HW2];
  const int t = threadIdx.x;
  const int n0 = blockIdx.x * 128;
  for (int c = t; c < 128 * 8; c += 256) {
    int row = c >> 3, seg = c & 7;
    int rowg = n0 + row;
    h8 v = (h8){0, 0, 0, 0, 0, 0, 0, 0};
    if (rowg < NN) v = *reinterpret_cast<const h8*>(gH1 + (size_t)rowg * 64 + seg * 8);
    *reinterpret_cast<h8*>(As + row * HW2 + seg * 8) = v;
  }
  __syncthreads();
  const int w = t >> 6, lane = t & 63;
  const int quad = lane >> 4, l = lane & 15;
  f4v acc[2][12];
#pragma unroll
  for (int mt = 0; mt < 2; ++mt)
#pragma unroll
    for (int nt = 0; nt < 12; ++nt) acc[mt][nt] = (f4v){0.f, 0.f, 0.f, 0.f};
#pragma unroll
  for (int ks = 0; ks < 2; ++ks) {
    int k0 = ks * 32 + quad * 8;
    h8 a0 = *reinterpret_cast<const h8*>(As + (w * 32 + l) * HW2 + k0);
    h8 a1 = *reinterpret_cast<const h8*>(As + (w * 32 + 16 + l) * HW2 + k0);
#pragma unroll
    for (int nt = 0; nt < 12; ++nt) {
      h8 b = *reinterpret_cast<const h8*>(BtH2 + (size_t)(nt * 16 + l) * 64 + k0);
      acc[0][nt] = __builtin_amdgcn_mfma_f32_16x16x32_f16(a0, b, acc[0][nt], 0, 0, 0);
      acc[1][nt] = __builtin_amdgcn_mfma_f32_16x16x32_f16(a1, b, acc[1][nt], 0, 0, 0);
    }
  }
#pragma unroll
  for (int mt = 0; mt < 2; ++mt) {
#pragma unroll
    for (int r = 0; r < 4; ++r) {
      int row = n0 + w * 32 + mt * 16 + quad * 4 + r;
      if (row < NN) {
        float dv = dinv[row];
#pragma unroll
        for (int nt2 = 0; nt2 < 4; ++nt2) {
          int col = nt2 * 16 + l;
          gV02[(size_t)row * 64 + col] = __float2half_rn(acc[mt][nt2][r]);
          gA2[(size_t)row * 64 + col] = __float2half_rn(acc[mt][4 + nt2][r]);
          gB2s[(size_t)row * 64 + col] = __float2half_rn(dv * acc[mt][8 + nt2][r]);
        }
      }
    }
  }
}

// ---------------------------------------------------------------------------
// Gather core (R5 style): wave per node, lane = dim, 4 acc chains, unroll 8.
#define GATHER_SUM(tbl)                                                    \
  int p0 = rp[node], p1 = rp[node + 1];                                    \
  float a0 = 0.f, a1 = 0.f, a2 = 0.f, a3 = 0.f;                            \
  int p = p0;                                                              \
  int pA = (p0 + 3) & ~3;                                                  \
  if (pA > p1) pA = p1;                                                    \
  for (; p < pA; ++p) a0 += h2f(tbl[(size_t)adj[p] * 64 + d]);             \
  for (; p + 8 <= p1; p += 8) {                                            \
    int4 e0 = *reinterpret_cast<const int4*>(adj + p);                     \
    int4 e1 = *reinterpret_cast<const int4*>(adj + p + 4);                 \
    a0 += h2f(tbl[(size_t)e0.x * 64 + d]);                                 \
    a1 += h2f(tbl[(size_t)e0.y * 64 + d]);                                 \
    a2 += h2f(tbl[(size_t)e0.z * 64 + d]);                                 \
    a3 += h2f(tbl[(size_t)e0.w * 64 + d]);                                 \
    a0 += h2f(tbl[(size_t)e1.x * 64 + d]);                                 \
    a1 += h2f(tbl[(size_t)e1.y * 64 + d]);                                 \
    a2 += h2f(tbl[(size_t)e1.z * 64 + d]);                                 \
    a3 += h2f(tbl[(size_t)e1.w * 64 + d]);                                 \
  }                                                                        \
  if (p + 4 <= p1) {                                                       \
    int4 e = *reinterpret_cast<const int4*>(adj + p);                      \
    a0 += h2f(tbl[(size_t)e.x * 64 + d]);                                  \
    a1 += h2f(tbl[(size_t)e.y * 64 + d]);                                  \
    a2 += h2f(tbl[(size_t)e.z * 64 + d]);                                  \
    a3 += h2f(tbl[(size_t)e.w * 64 + d]);                                  \
    p += 4;                                                                \
  }                                                                        \
  for (; p < p1; ++p) a1 += h2f(tbl[(size_t)adj[p] * 64 + d]);             \
  float s = (a0 + a1) + (a2 + a3);

// prop A/C: t = -dv*sum(tbl); out = fp16(dv*(aux + 2t))
__global__ __launch_bounds__(256) void k_propA(const int* __restrict__ rp,
                                               const int* __restrict__ adj,
                                               const __half* __restrict__ tbl,
                                               const __half* __restrict__ aux,
                                               const float* __restrict__ dinv,
                                               __half* __restrict__ outT) {
  int node = blockIdx.x * 4 + (threadIdx.x >> 6);
  int d = threadIdx.x & 63;
  if (node >= NN) return;
  GATHER_SUM(tbl)
  float dv = dinv[node];
  float tt = -dv * s;
  size_t idx = (size_t)node * 64 + d;
  outT[idx] = __float2half_rn(dv * (h2f(aux[idx]) + 2.f * tt));
}

// prop B: r = -dv*sum(tbl); h1 = relu(V0 + r + b1)
__global__ __launch_bounds__(256) void k_propB(const int* __restrict__ rp,
                                               const int* __restrict__ adj,
                                               const __half* __restrict__ tbl,
                                               const __half* __restrict__ gV0,
                                               const float* __restrict__ b1v,
                                               const float* __restrict__ dinv,
                                               __half* __restrict__ gH1) {
  int node = blockIdx.x * 4 + (threadIdx.x >> 6);
  int d = threadIdx.x & 63;
  if (node >= NN) return;
  GATHER_SUM(tbl)
  float dv = dinv[node];
  float r = -dv * s;
  size_t idx = (size_t)node * 64 + d;
  float h = fmaxf(h2f(gV0[idx]) + r + b1v[d], 0.f);
  gH1[idx] = __float2half_rn(h);
}

// prop D: r = -dv*sum(tbl); h2 = relu(V02 + r + b2); pool atomics (f32).
__global__ __launch_bounds__(256) void k_propD(const int* __restrict__ rp,
                                               const int* __restrict__ adj,
                                               const __half* __restrict__ tbl,
                                               const __half* __restrict__ gV02,
                                               const float* __restrict__ b2v,
                                               const float* __restrict__ dinv,
                                               const int* __restrict__ b32,
                                               float* __restrict__ pooled) {
  int node = blockIdx.x * 4 + (threadIdx.x >> 6);
  int d = threadIdx.x & 63;
  if (node >= NN) return;
  GATHER_SUM(tbl)
  float dv = dinv[node];
  float r = -dv * s;
  size_t idx = (size_t)node * 64 + d;
  float h = fmaxf(h2f(gV02[idx]) + r + b2v[d], 0.f);
  int g = b32[node];
  atomAddF(&pooled[g * 64 + d], h);
}

// Final: out[g] = dot(pooled[g]/max(cnt,1), Wfc) + bfc
__global__ void k_out(const float* __restrict__ pooled, const int* __restrict__ gcnt,
                      const float* __restrict__ Wfc, const float* __restrict__ bfc,
                      float* __restrict__ out) {
  int g = blockIdx.x, t = threadIdx.x;  // 64 threads
  float v = pooled[g * 64 + t] * Wfc[t];
  int c = gcnt[g];
  v /= (float)(c > 0 ? c : 1);
  for (int off = 32; off > 0; off >>= 1) v += __shfl_down(v, off, 64);
  if (t == 0) out[g] = v + bfc[0];
}

// ---------------------------------------------------------------------------
extern "C" void kernel_launch(void* const* d_in, const int* in_sizes, int n_in,
                              void* d_out, int out_size, void* d_ws, size_t ws_size,
                              hipStream_t stream) {
  const float* x   = (const float*)d_in[0];
  const void*  ei  = d_in[1];
  const void*  bat = d_in[2];
  const float* W1  = (const float*)d_in[3];
  const float* b1v = (const float*)d_in[4];
  const float* W2  = (const float*)d_in[5];
  const float* b2v = (const float*)d_in[6];
  const float* Wfc = (const float*)d_in[7];
  const float* bfc = (const float*)d_in[8];
  float* out = (float*)d_out;

  char* w = (char*)d_ws;
  size_t o = 0;
  auto take = [&](size_t bytes) -> void* {
    void* p = w + o;
    o = (o + bytes + 255) & ~(size_t)255;
    return p;
  };
  int*      flag   = (int*)take(256);
  // ---- zero region start
  int*      gcnt   = (int*)take((size_t)NG * 4);
  float*    pooled = (float*)take((size_t)NG * 64 * 4);
  int*      sCnt   = (int*)take((size_t)(NBK + 2) * 4);
  int*      dCnt   = (int*)take((size_t)(NBK + 2) * 4);
  // ---- zero region end
  char*     zend   = w + o;
  int*      sBase  = (int*)take((size_t)(NBK + 2) * 4);
  int*      dBase  = (int*)take((size_t)(NBK + 2) * 4);
  int*      sCur   = (int*)take((size_t)(NBK + 2) * 4);
  int*      dCur   = (int*)take((size_t)(NBK + 2) * 4);
  int*      b32    = (int*)take((size_t)NN * 4);
  float*    dinv   = (float*)take((size_t)NN * 4);
  int*      rowptr = (int*)take((size_t)(NN + 2) * 4);
  int*      hsBlk  = (int*)take((size_t)256 * NBK * 4);
  int*      hdBlk  = (int*)take((size_t)256 * NBK * 4);
  int*      srclist= (int*)take((size_t)NE * 4);
  unsigned* elist  = (unsigned*)take((size_t)NE * 4);
  int*      adj    = (int*)take((size_t)NE * 4);   // distinct: no race with srclist
  __half*   BtX    = (__half*)take((size_t)192 * 128 * 2);
  __half*   BtH2   = (__half*)take((size_t)192 * 64 * 2);
  __half*   gV0    = (__half*)take((size_t)NN * 64 * 2);
  __half*   gA1    = (__half*)take((size_t)NN * 64 * 2);
  __half*   gU2s   = (__half*)take((size_t)NN * 64 * 2);
  __half*   gM1    = (__half*)take((size_t)NN * 64 * 2);
  __half*   gH1    = (__half*)take((size_t)NN * 64 * 2);
  // aliases for layer 2 (source buffers dead by then):
  __half*   gV02   = gU2s;  // dead after propA
  __half*   gA2    = gA1;   // dead after propA
  __half*   gB2s   = gV0;   // dead after propB
  __half*   gM2    = gM1;   // dead after propB
  (void)in_sizes; (void)n_in; (void)out_size; (void)ws_size;

  hipMemsetAsync(gcnt, 0, (size_t)(zend - (char*)gcnt), stream);

  k_detect<<<1, 64, 0, stream>>>((const int*)ei, flag);
  k_front<<<GB_BATCH + GB_PREPW + GB_HIST, 256, 0, stream>>>(
      bat, ei, flag, W1, W2, b32, gcnt, BtX, BtH2, sCnt, dCnt, hsBlk, hdBlk);
  k_scan<<<1, 1024, 0, stream>>>(sCnt, dCnt, sBase, dBase, sCur, dCur);
  k_scatter<<<256, 256, 0, stream>>>(ei, flag, hsBlk, hdBlk, sCur, dCur, srclist, elist);
  k_back<<<2 * NBK, 256, 0, stream>>>(sBase, srclist, dinv, dBase, elist, rowptr, adj);

  const int gemm_grid = (NN + 127) / 128;  // 782
  const int prop_grid = (NN + 3) / 4;      // 25000

  // Layer 1: V0 | a1 | U2s, then lhat(a1 + 2*lhat(...)) via two 1-line rounds
  k_gemm_x<<<gemm_grid, 256, 0, stream>>>(x, BtX, dinv, gV0, gA1, gU2s);
  k_propA<<<prop_grid, 256, 0, stream>>>(rowptr, adj, gU2s, gA1, dinv, gM1);
  k_propB<<<prop_grid, 256, 0, stream>>>(rowptr, adj, gM1, gV0, b1v, dinv, gH1);
  // Layer 2: V02 | a2 | b2s, then two 1-line rounds, pool fused in last round
  k_gemm_h<<<gemm_grid, 256, 0, stream>>>(gH1, BtH2, dinv, gV02, gA2, gB2s);
  k_propA<<<prop_grid, 256, 0, stream>>>(rowptr, adj, gB2s, gA2, dinv, gM2);
  k_propD<<<prop_grid, 256, 0, stream>>>(rowptr, adj, gM2, gV02, b2v, dinv, b32, pooled);
  k_out<<<NG, 64, 0, stream>>>(pooled, gcnt, Wfc, bfc, out);
}

// Round 8
// 633.393 us; speedup vs baseline: 1.0940x; 1.0940x over previous
//
#include <hip/hip_runtime.h>
#include <hip/hip_fp16.h>
#include <cstdint>
#include <cstddef>

// Problem constants (fixed by the reference)
static constexpr int NN = 100000;   // nodes
static constexpr int NE = 3200000;  // edges
static constexpr int NG = 256;      // graphs
static constexpr int NBK = (NN + 127) / 128;  // dst/src buckets of 128 nodes = 782
static constexpr int EPB = NE / 256;          // edges per hist/scatter block = 12500
static constexpr int GB_BATCH = (NN + 255) / 256;                    // 391
static constexpr int GB_PREPW = (192 * 128 + 192 * 64 + 255) / 256;  // 144
static constexpr int GB_HIST = 256;

typedef _Float16 h8 __attribute__((ext_vector_type(8)));
typedef float f4v __attribute__((ext_vector_type(4)));

__device__ __forceinline__ void atomAddF(float* p, float v) {
  unsafeAtomicAdd(p, v);  // native global_atomic_add_f32 on gfx950
}
__device__ __forceinline__ float h2f(__half h) { return __half2float(h); }

// ---------------------------------------------------------------------------
// dtype hedge: reference says int64, harness doc says int32. Detect at runtime.
__global__ void k_detect(const int* __restrict__ ei, int* __restrict__ flag) {
  if (threadIdx.x == 0 && blockIdx.x == 0) {
    int nz = 0;
    for (int i = 0; i < 64; ++i) nz += (ei[2 * i + 1] != 0) ? 1 : 0;
    *flag = (nz == 0) ? 1 : 0;  // 1 => int64 layout
  }
}

__device__ __forceinline__ int ld_idx(const void* raw, int f, int i) {
  return f ? (int)((const long long*)raw)[i] : ((const int*)raw)[i];
}

// ---------------------------------------------------------------------------
// Front kernel: blockIdx ranges -> [batch repack+gcnt | weight prep | edge hist]
__global__ __launch_bounds__(256) void k_front(const void* __restrict__ bat,
                                               const void* __restrict__ ei,
                                               const int* __restrict__ flag,
                                               const float* __restrict__ W1,
                                               const float* __restrict__ W2,
                                               int* __restrict__ b32,
                                               int* __restrict__ gcnt,
                                               __half* __restrict__ BtX,
                                               __half* __restrict__ BtH2,
                                               int* __restrict__ sCnt,
                                               int* __restrict__ dCnt,
                                               int* __restrict__ hsBlk,
                                               int* __restrict__ hdBlk) {
  __shared__ int sh[2 * NBK];
  int b = blockIdx.x;
  int t = threadIdx.x;
  if (b < GB_BATCH) {
    int* cnt = sh;
    cnt[t] = 0;
    int blk0 = b * 256;
    int f = *flag;
    int g0 = ld_idx(bat, f, blk0);
    __syncthreads();
    int i = blk0 + t;
    if (i < NN) {
      int g = ld_idx(bat, f, i);
      b32[i] = g;
      atomicAdd(&cnt[g - g0], 1);
    }
    __syncthreads();
    if (cnt[t] > 0) atomicAdd(&gcnt[g0 + t], cnt[t]);
  } else if (b < GB_BATCH + GB_PREPW) {
    // BtX[192][128]: rows 0-63=(W1_0-W1_2)^T, 64-127=W1_1^T, 128-191=W1_2^T
    // BtH2[192][64]: rows 0-63=(W2_0-W2_2)^T, 64-127=W2_1^T, 128-191=W2_2^T
    int u = (b - GB_BATCH) * 256 + t;
    if (u < 192 * 128) {
      int n = u >> 7, k = u & 127;
      float v;
      if (n < 64)       v = W1[k * 64 + n] - W1[16384 + k * 64 + n];
      else if (n < 128) v = W1[8192 + k * 64 + (n - 64)];
      else              v = W1[16384 + k * 64 + (n - 128)];
      BtX[n * 128 + k] = __float2half_rn(v);
    } else if (u < 192 * 128 + 192 * 64) {
      int u2 = u - 192 * 128;
      int n = u2 >> 6, k = u2 & 63;
      float v;
      if (n < 64)       v = W2[k * 64 + n] - W2[8192 + k * 64 + n];
      else if (n < 128) v = W2[4096 + k * 64 + (n - 64)];
      else              v = W2[8192 + k * 64 + (n - 128)];
      BtH2[n * 64 + k] = __float2half_rn(v);
    }
  } else {
    int hb = b - GB_BATCH - GB_PREPW;
    int* hs = sh;
    int* hd = sh + NBK;
    for (int i = t; i < NBK; i += 256) { hs[i] = 0; hd[i] = 0; }
    __syncthreads();
    int f = *flag;
    int e0 = hb * EPB;
    for (int e = e0 + t; e < e0 + EPB; e += 256) {
      int s = ld_idx(ei, f, e);
      int d = ld_idx(ei, f, NE + e);
      atomicAdd(&hs[s >> 7], 1);
      atomicAdd(&hd[d >> 7], 1);
    }
    __syncthreads();
    size_t hoff = (size_t)hb * NBK;
    for (int i = t; i < NBK; i += 256) {
      int a = hs[i], c = hd[i];
      hsBlk[hoff + i] = a;
      hdBlk[hoff + i] = c;
      if (a) atomicAdd(&sCnt[i], a);
      if (c) atomicAdd(&dCnt[i], c);
    }
  }
}

// Exclusive scan of both bucket-count arrays (782 <= 1024, one block).
__global__ __launch_bounds__(1024) void k_scan(const int* __restrict__ sCnt,
                                               const int* __restrict__ dCnt,
                                               int* __restrict__ sBase,
                                               int* __restrict__ dBase,
                                               int* __restrict__ sCur,
                                               int* __restrict__ dCur) {
  __shared__ int sh1[1024], sh2[1024];
  int t = threadIdx.x;
  int v1 = (t < NBK) ? sCnt[t] : 0;
  int v2 = (t < NBK) ? dCnt[t] : 0;
  sh1[t] = v1; sh2[t] = v2;
  __syncthreads();
  for (int off = 1; off < 1024; off <<= 1) {
    int a1 = (t >= off) ? sh1[t - off] : 0;
    int a2 = (t >= off) ? sh2[t - off] : 0;
    __syncthreads();
    sh1[t] += a1; sh2[t] += a2;
    __syncthreads();
  }
  if (t <= NBK) {
    int b1 = sh1[t] - v1, b2 = sh2[t] - v2;  // exclusive
    sBase[t] = b1; dBase[t] = b2;
    if (t < NBK) { sCur[t] = b1; dCur[t] = b2; }
  }
}

// Pass 2: chunk-reserve per (block,bucket) using saved per-block hists,
// scatter src ids (by src bucket) and packed (src | dst_local<<17) records.
__global__ __launch_bounds__(256) void k_scatter(const void* __restrict__ raw,
                                                 const int* __restrict__ flag,
                                                 const int* __restrict__ hsBlk,
                                                 const int* __restrict__ hdBlk,
                                                 int* __restrict__ sCur,
                                                 int* __restrict__ dCur,
                                                 int* __restrict__ srclist,
                                                 unsigned* __restrict__ elist) {
  __shared__ int hs[NBK], hd[NBK], cbS[NBK], cbD[NBK];
  int t = threadIdx.x;
  size_t hb = (size_t)blockIdx.x * NBK;
  for (int i = t; i < NBK; i += 256) {
    int c1 = hsBlk[hb + i];
    cbS[i] = c1 ? atomicAdd(&sCur[i], c1) : 0;
    int c2 = hdBlk[hb + i];
    cbD[i] = c2 ? atomicAdd(&dCur[i], c2) : 0;
    hs[i] = 0; hd[i] = 0;
  }
  __syncthreads();
  int f = *flag;
  int e0 = blockIdx.x * EPB;
  for (int e = e0 + t; e < e0 + EPB; e += 256) {
    int s = ld_idx(raw, f, e);
    int d = ld_idx(raw, f, NE + e);
    int bs = s >> 7, bd = d >> 7;
    int ls = atomicAdd(&hs[bs], 1);
    int ld2 = atomicAdd(&hd[bd], 1);
    srclist[cbS[bs] + ls] = s;
    elist[cbD[bd] + ld2] = (unsigned)s | ((unsigned)(d & 127) << 17);
  }
}

// Back kernel: [out-degree -> dinv | per-bucket counting sort -> CSR]
__global__ __launch_bounds__(256) void k_back(const int* __restrict__ sBase,
                                              const int* __restrict__ srclist,
                                              float* __restrict__ dinv,
                                              const int* __restrict__ dBase,
                                              const unsigned* __restrict__ elist,
                                              int* __restrict__ rowptr,
                                              int* __restrict__ adj) {
  __shared__ int cnt[128], sc[128], off[128], fill[128];
  int t = threadIdx.x;
  int bb = blockIdx.x;
  if (bb < NBK) {
    int b = bb;
    if (t < 128) cnt[t] = 0;
    __syncthreads();
    int e0 = sBase[b], e1 = sBase[b + 1];
    for (int i = e0 + t; i < e1; i += 256) atomicAdd(&cnt[srclist[i] & 127], 1);
    __syncthreads();
    if (t < 128) {
      int node = b * 128 + t;
      if (node < NN) {
        int c = cnt[t];
        dinv[node] = (c > 0) ? rsqrtf((float)c) : 0.f;
      }
    }
  } else {
    int b = bb - NBK;
    if (t < 128) { cnt[t] = 0; fill[t] = 0; }
    __syncthreads();
    int e0 = dBase[b], e1 = dBase[b + 1];
    for (int i = e0 + t; i < e1; i += 256) atomicAdd(&cnt[elist[i] >> 17], 1);
    __syncthreads();
    if (t < 128) sc[t] = cnt[t];
    __syncthreads();
    for (int o = 1; o < 128; o <<= 1) {
      int a = (t < 128 && t >= o) ? sc[t - o] : 0;
      __syncthreads();
      if (t < 128) sc[t] += a;
      __syncthreads();
    }
    if (t < 128) {
      off[t] = sc[t] - cnt[t];  // exclusive
      int node = b * 128 + t;
      if (node < NN) rowptr[node] = e0 + off[t];
    }
    if (b == NBK - 1 && t == 0) rowptr[NN] = e1;
    __syncthreads();
    for (int i = e0 + t; i < e1; i += 256) {
      unsigned w2 = elist[i];
      int l = (int)(w2 >> 17);
      int pos = atomicAdd(&fill[l], 1);
      adj[e0 + off[l] + pos] = (int)(w2 & 0x1FFFFu);
    }
  }
}

// ---------------------------------------------------------------------------
// MFMA GEMM X: [128 nodes] x [K=128] x [N=192].
// Outputs (all fp16): gV0 = x@(W1_0-W1_2), gA1 = x@W1_1, gU2s = dinv.*(x@W1_2).
static constexpr int AW = 136;  // LDS row stride (halves)
__global__ __launch_bounds__(256) void k_gemm_x(const float* __restrict__ x,
                                                const __half* __restrict__ BtX,
                                                const float* __restrict__ dinv,
                                                __half* __restrict__ gV0,
                                                __half* __restrict__ gA1,
                                                __half* __restrict__ gU2s) {
  __shared__ __align__(16) _Float16 As[128 * AW];
  const int t = threadIdx.x;
  const int n0 = blockIdx.x * 128;
  {
    int i = t >> 1, q = t & 1;
    int row = n0 + i;
    _Float16* dst = As + i * AW + q * 64;
    if (row < NN) {
      const float* src = x + (size_t)row * 128 + q * 64;
#pragma unroll
      for (int c = 0; c < 64; c += 4) {
        float4 v = *reinterpret_cast<const float4*>(src + c);
        ushort4 u;
        u.x = __half_as_ushort(__float2half_rn(v.x));
        u.y = __half_as_ushort(__float2half_rn(v.y));
        u.z = __half_as_ushort(__float2half_rn(v.z));
        u.w = __half_as_ushort(__float2half_rn(v.w));
        *reinterpret_cast<ushort4*>(dst + c) = u;
      }
    } else {
#pragma unroll
      for (int c = 0; c < 64; c += 4)
        *reinterpret_cast<ushort4*>(dst + c) = make_ushort4(0, 0, 0, 0);
    }
  }
  __syncthreads();
  const int w = t >> 6, lane = t & 63;
  const int quad = lane >> 4, l = lane & 15;
  f4v acc[2][12];
#pragma unroll
  for (int mt = 0; mt < 2; ++mt)
#pragma unroll
    for (int nt = 0; nt < 12; ++nt) acc[mt][nt] = (f4v){0.f, 0.f, 0.f, 0.f};

#pragma unroll
  for (int ks = 0; ks < 4; ++ks) {
    int k0 = ks * 32 + quad * 8;
    h8 a0 = *reinterpret_cast<const h8*>(As + (w * 32 + l) * AW + k0);
    h8 a1 = *reinterpret_cast<const h8*>(As + (w * 32 + 16 + l) * AW + k0);
#pragma unroll
    for (int nt = 0; nt < 12; ++nt) {
      h8 b = *reinterpret_cast<const h8*>(BtX + (size_t)(nt * 16 + l) * 128 + k0);
      acc[0][nt] = __builtin_amdgcn_mfma_f32_16x16x32_f16(a0, b, acc[0][nt], 0, 0, 0);
      acc[1][nt] = __builtin_amdgcn_mfma_f32_16x16x32_f16(a1, b, acc[1][nt], 0, 0, 0);
    }
  }
#pragma unroll
  for (int mt = 0; mt < 2; ++mt) {
#pragma unroll
    for (int r = 0; r < 4; ++r) {
      int row = n0 + w * 32 + mt * 16 + quad * 4 + r;
      if (row < NN) {
        float dv = dinv[row];
#pragma unroll
        for (int nt2 = 0; nt2 < 4; ++nt2) {
          int col = nt2 * 16 + l;
          gV0[(size_t)row * 64 + col] = __float2half_rn(acc[mt][nt2][r]);
          gA1[(size_t)row * 64 + col] = __float2half_rn(acc[mt][4 + nt2][r]);
          gU2s[(size_t)row * 64 + col] = __float2half_rn(dv * acc[mt][8 + nt2][r]);
        }
      }
    }
  }
}

// ---------------------------------------------------------------------------
// MFMA GEMM H: [128 nodes] x [K=64] x [N=192] on h1.
static constexpr int HW2 = 72;  // LDS row stride (halves)
__global__ __launch_bounds__(256) void k_gemm_h(const __half* __restrict__ gH1,
                                                const __half* __restrict__ BtH2,
                                                const float* __restrict__ dinv,
                                                __half* __restrict__ gV02,
                                                __half* __restrict__ gA2,
                                                __half* __restrict__ gB2s) {
  __shared__ __align__(16) _Float16 As[128 * HW2];
  const int t = threadIdx.x;
  const int n0 = blockIdx.x * 128;
  for (int c = t; c < 128 * 8; c += 256) {
    int row = c >> 3, seg = c & 7;
    int rowg = n0 + row;
    h8 v = (h8){0, 0, 0, 0, 0, 0, 0, 0};
    if (rowg < NN) v = *reinterpret_cast<const h8*>(gH1 + (size_t)rowg * 64 + seg * 8);
    *reinterpret_cast<h8*>(As + row * HW2 + seg * 8) = v;
  }
  __syncthreads();
  const int w = t >> 6, lane = t & 63;
  const int quad = lane >> 4, l = lane & 15;
  f4v acc[2][12];
#pragma unroll
  for (int mt = 0; mt < 2; ++mt)
#pragma unroll
    for (int nt = 0; nt < 12; ++nt) acc[mt][nt] = (f4v){0.f, 0.f, 0.f, 0.f};
#pragma unroll
  for (int ks = 0; ks < 2; ++ks) {
    int k0 = ks * 32 + quad * 8;
    h8 a0 = *reinterpret_cast<const h8*>(As + (w * 32 + l) * HW2 + k0);
    h8 a1 = *reinterpret_cast<const h8*>(As + (w * 32 + 16 + l) * HW2 + k0);
#pragma unroll
    for (int nt = 0; nt < 12; ++nt) {
      h8 b = *reinterpret_cast<const h8*>(BtH2 + (size_t)(nt * 16 + l) * 64 + k0);
      acc[0][nt] = __builtin_amdgcn_mfma_f32_16x16x32_f16(a0, b, acc[0][nt], 0, 0, 0);
      acc[1][nt] = __builtin_amdgcn_mfma_f32_16x16x32_f16(a1, b, acc[1][nt], 0, 0, 0);
    }
  }
#pragma unroll
  for (int mt = 0; mt < 2; ++mt) {
#pragma unroll
    for (int r = 0; r < 4; ++r) {
      int row = n0 + w * 32 + mt * 16 + quad * 4 + r;
      if (row < NN) {
        float dv = dinv[row];
#pragma unroll
        for (int nt2 = 0; nt2 < 4; ++nt2) {
          int col = nt2 * 16 + l;
          gV02[(size_t)row * 64 + col] = __float2half_rn(acc[mt][nt2][r]);
          gA2[(size_t)row * 64 + col] = __float2half_rn(acc[mt][4 + nt2][r]);
          gB2s[(size_t)row * 64 + col] = __float2half_rn(dv * acc[mt][8 + nt2][r]);
        }
      }
    }
  }
}

// ---------------------------------------------------------------------------
// Gather core: wave per node, lane = dim, 16 outstanding lines, 8 acc chains.
#define GATHER_SUM(tbl)                                                    \
  int p0 = rp[node], p1 = rp[node + 1];                                    \
  float a0 = 0.f, a1 = 0.f, a2 = 0.f, a3 = 0.f;                            \
  float a4 = 0.f, a5 = 0.f, a6 = 0.f, a7 = 0.f;                            \
  int p = p0;                                                              \
  int pA = (p0 + 3) & ~3;                                                  \
  if (pA > p1) pA = p1;                                                    \
  for (; p < pA; ++p) a0 += h2f(tbl[(size_t)adj[p] * 64 + d]);             \
  for (; p + 16 <= p1; p += 16) {                                          \
    int4 e0 = *reinterpret_cast<const int4*>(adj + p);                     \
    int4 e1 = *reinterpret_cast<const int4*>(adj + p + 4);                 \
    int4 e2 = *reinterpret_cast<const int4*>(adj + p + 8);                 \
    int4 e3 = *reinterpret_cast<const int4*>(adj + p + 12);                \
    __half v0 = tbl[(size_t)e0.x * 64 + d];                                \
    __half v1 = tbl[(size_t)e0.y * 64 + d];                                \
    __half v2 = tbl[(size_t)e0.z * 64 + d];                                \
    __half v3 = tbl[(size_t)e0.w * 64 + d];                                \
    __half v4 = tbl[(size_t)e1.x * 64 + d];                                \
    __half v5 = tbl[(size_t)e1.y * 64 + d];                                \
    __half v6 = tbl[(size_t)e1.z * 64 + d];                                \
    __half v7 = tbl[(size_t)e1.w * 64 + d];                                \
    __half v8 = tbl[(size_t)e2.x * 64 + d];                                \
    __half v9 = tbl[(size_t)e2.y * 64 + d];                                \
    __half va = tbl[(size_t)e2.z * 64 + d];                                \
    __half vb = tbl[(size_t)e2.w * 64 + d];                                \
    __half vc = tbl[(size_t)e3.x * 64 + d];                                \
    __half vd = tbl[(size_t)e3.y * 64 + d];                                \
    __half ve = tbl[(size_t)e3.z * 64 + d];                                \
    __half vf = tbl[(size_t)e3.w * 64 + d];                                \
    a0 += h2f(v0); a1 += h2f(v1); a2 += h2f(v2); a3 += h2f(v3);            \
    a4 += h2f(v4); a5 += h2f(v5); a6 += h2f(v6); a7 += h2f(v7);            \
    a0 += h2f(v8); a1 += h2f(v9); a2 += h2f(va); a3 += h2f(vb);            \
    a4 += h2f(vc); a5 += h2f(vd); a6 += h2f(ve); a7 += h2f(vf);            \
  }                                                                        \
  if (p + 8 <= p1) {                                                       \
    int4 e0 = *reinterpret_cast<const int4*>(adj + p);                     \
    int4 e1 = *reinterpret_cast<const int4*>(adj + p + 4);                 \
    a0 += h2f(tbl[(size_t)e0.x * 64 + d]);                                 \
    a1 += h2f(tbl[(size_t)e0.y * 64 + d]);                                 \
    a2 += h2f(tbl[(size_t)e0.z * 64 + d]);                                 \
    a3 += h2f(tbl[(size_t)e0.w * 64 + d]);                                 \
    a4 += h2f(tbl[(size_t)e1.x * 64 + d]);                                 \
    a5 += h2f(tbl[(size_t)e1.y * 64 + d]);                                 \
    a6 += h2f(tbl[(size_t)e1.z * 64 + d]);                                 \
    a7 += h2f(tbl[(size_t)e1.w * 64 + d]);                                 \
    p += 8;                                                                \
  }                                                                        \
  if (p + 4 <= p1) {                                                       \
    int4 e = *reinterpret_cast<const int4*>(adj + p);                      \
    a0 += h2f(tbl[(size_t)e.x * 64 + d]);                                  \
    a1 += h2f(tbl[(size_t)e.y * 64 + d]);                                  \
    a2 += h2f(tbl[(size_t)e.z * 64 + d]);                                  \
    a3 += h2f(tbl[(size_t)e.w * 64 + d]);                                  \
    p += 4;                                                                \
  }                                                                        \
  for (; p < p1; ++p) a1 += h2f(tbl[(size_t)adj[p] * 64 + d]);             \
  float s = ((a0 + a1) + (a2 + a3)) + ((a4 + a5) + (a6 + a7));

// prop A/C: t = -dv*sum(tbl); out = fp16(dv*(aux + 2t))
__global__ __launch_bounds__(256, 8) void k_propA(const int* __restrict__ rp,
                                                  const int* __restrict__ adj,
                                                  const __half* __restrict__ tbl,
                                                  const __half* __restrict__ aux,
                                                  const float* __restrict__ dinv,
                                                  __half* __restrict__ outT) {
  int node = blockIdx.x * 4 + (threadIdx.x >> 6);
  int d = threadIdx.x & 63;
  if (node >= NN) return;
  GATHER_SUM(tbl)
  float dv = dinv[node];
  float tt = -dv * s;
  size_t idx = (size_t)node * 64 + d;
  outT[idx] = __float2half_rn(dv * (h2f(aux[idx]) + 2.f * tt));
}

// prop B: r = -dv*sum(tbl); h1 = relu(V0 + r + b1)
__global__ __launch_bounds__(256, 8) void k_propB(const int* __restrict__ rp,
                                                  const int* __restrict__ adj,
                                                  const __half* __restrict__ tbl,
                                                  const __half* __restrict__ gV0,
                                                  const float* __restrict__ b1v,
                                                  const float* __restrict__ dinv,
                                                  __half* __restrict__ gH1) {
  int node = blockIdx.x * 4 + (threadIdx.x >> 6);
  int d = threadIdx.x & 63;
  if (node >= NN) return;
  GATHER_SUM(tbl)
  float dv = dinv[node];
  float r = -dv * s;
  size_t idx = (size_t)node * 64 + d;
  float h = fmaxf(h2f(gV0[idx]) + r + b1v[d], 0.f);
  gH1[idx] = __float2half_rn(h);
}

// prop D: r = -dv*sum(tbl); h2 = relu(V02 + r + b2) -> fp16 table (no atomics).
__global__ __launch_bounds__(256, 8) void k_propD(const int* __restrict__ rp,
                                                  const int* __restrict__ adj,
                                                  const __half* __restrict__ tbl,
                                                  const __half* __restrict__ gV02,
                                                  const float* __restrict__ b2v,
                                                  const float* __restrict__ dinv,
                                                  __half* __restrict__ gH2) {
  int node = blockIdx.x * 4 + (threadIdx.x >> 6);
  int d = threadIdx.x & 63;
  if (node >= NN) return;
  GATHER_SUM(tbl)
  float dv = dinv[node];
  float r = -dv * s;
  size_t idx = (size_t)node * 64 + d;
  float h = fmaxf(h2f(gV02[idx]) + r + b2v[d], 0.f);
  gH2[idx] = __float2half_rn(h);
}

// Pool: batch sorted -> run-length reduce 32 rows per wave, ~2 atomics each.
__global__ __launch_bounds__(256) void k_pool(const __half* __restrict__ gH2,
                                              const int* __restrict__ b32,
                                              float* __restrict__ pooled) {
  __shared__ int gb[128];
  int t = threadIdx.x;
  int n0 = blockIdx.x * 128;
  if (t < 128) gb[t] = (n0 + t < NN) ? b32[n0 + t] : -1;
  __syncthreads();
  int rg = t >> 6, d = t & 63;
  int base = rg * 32;
  int cur = -2;
  float s = 0.f;
  for (int i = 0; i < 32; ++i) {
    int g = gb[base + i];  // wave-uniform
    float v = (g >= 0) ? h2f(gH2[(size_t)(n0 + base + i) * 64 + d]) : 0.f;
    if (g != cur) {
      if (cur >= 0) atomAddF(&pooled[cur * 64 + d], s);
      s = 0.f;
      cur = g;
    }
    s += v;
  }
  if (cur >= 0) atomAddF(&pooled[cur * 64 + d], s);
}

// Final: out[g] = dot(pooled[g]/max(cnt,1), Wfc) + bfc
__global__ void k_out(const float* __restrict__ pooled, const int* __restrict__ gcnt,
                      const float* __restrict__ Wfc, const float* __restrict__ bfc,
                      float* __restrict__ out) {
  int g = blockIdx.x, t = threadIdx.x;  // 64 threads
  float v = pooled[g * 64 + t] * Wfc[t];
  int c = gcnt[g];
  v /= (float)(c > 0 ? c : 1);
  for (int off = 32; off > 0; off >>= 1) v += __shfl_down(v, off, 64);
  if (t == 0) out[g] = v + bfc[0];
}

// ---------------------------------------------------------------------------
extern "C" void kernel_launch(void* const* d_in, const int* in_sizes, int n_in,
                              void* d_out, int out_size, void* d_ws, size_t ws_size,
                              hipStream_t stream) {
  const float* x   = (const float*)d_in[0];
  const void*  ei  = d_in[1];
  const void*  bat = d_in[2];
  const float* W1  = (const float*)d_in[3];
  const float* b1v = (const float*)d_in[4];
  const float* W2  = (const float*)d_in[5];
  const float* b2v = (const float*)d_in[6];
  const float* Wfc = (const float*)d_in[7];
  const float* bfc = (const float*)d_in[8];
  float* out = (float*)d_out;

  char* w = (char*)d_ws;
  size_t o = 0;
  auto take = [&](size_t bytes) -> void* {
    void* p = w + o;
    o = (o + bytes + 255) & ~(size_t)255;
    return p;
  };
  int*      flag   = (int*)take(256);
  // ---- zero region start
  int*      gcnt   = (int*)take((size_t)NG * 4);
  float*    pooled = (float*)take((size_t)NG * 64 * 4);
  int*      sCnt   = (int*)take((size_t)(NBK + 2) * 4);
  int*      dCnt   = (int*)take((size_t)(NBK + 2) * 4);
  // ---- zero region end
  char*     zend   = w + o;
  int*      sBase  = (int*)take((size_t)(NBK + 2) * 4);
  int*      dBase  = (int*)take((size_t)(NBK + 2) * 4);
  int*      sCur   = (int*)take((size_t)(NBK + 2) * 4);
  int*      dCur   = (int*)take((size_t)(NBK + 2) * 4);
  int*      b32    = (int*)take((size_t)NN * 4);
  float*    dinv   = (float*)take((size_t)NN * 4);
  int*      rowptr = (int*)take((size_t)(NN + 2) * 4);
  int*      hsBlk  = (int*)take((size_t)256 * NBK * 4);
  int*      hdBlk  = (int*)take((size_t)256 * NBK * 4);
  int*      srclist= (int*)take((size_t)NE * 4);
  unsigned* elist  = (unsigned*)take((size_t)NE * 4);
  int*      adj    = (int*)take((size_t)NE * 4);
  __half*   BtX    = (__half*)take((size_t)192 * 128 * 2);
  __half*   BtH2   = (__half*)take((size_t)192 * 64 * 2);
  __half*   gV0    = (__half*)take((size_t)NN * 64 * 2);
  __half*   gA1    = (__half*)take((size_t)NN * 64 * 2);
  __half*   gU2s   = (__half*)take((size_t)NN * 64 * 2);
  __half*   gM1    = (__half*)take((size_t)NN * 64 * 2);
  __half*   gH1    = (__half*)take((size_t)NN * 64 * 2);
  // aliases for layer 2 (source buffers dead by then):
  __half*   gV02   = gU2s;  // dead after propA(1)
  __half*   gA2    = gA1;   // dead after propA(1)
  __half*   gB2s   = gV0;   // dead after propB
  __half*   gM2    = gM1;   // dead after propB... consumed by propD
  __half*   gH2    = gH1;   // gH1 dead after gemm_h
  (void)in_sizes; (void)n_in; (void)out_size; (void)ws_size;

  hipMemsetAsync(gcnt, 0, (size_t)(zend - (char*)gcnt), stream);

  k_detect<<<1, 64, 0, stream>>>((const int*)ei, flag);
  k_front<<<GB_BATCH + GB_PREPW + GB_HIST, 256, 0, stream>>>(
      bat, ei, flag, W1, W2, b32, gcnt, BtX, BtH2, sCnt, dCnt, hsBlk, hdBlk);
  k_scan<<<1, 1024, 0, stream>>>(sCnt, dCnt, sBase, dBase, sCur, dCur);
  k_scatter<<<256, 256, 0, stream>>>(ei, flag, hsBlk, hdBlk, sCur, dCur, srclist, elist);
  k_back<<<2 * NBK, 256, 0, stream>>>(sBase, srclist, dinv, dBase, elist, rowptr, adj);

  const int gemm_grid = (NN + 127) / 128;  // 782
  const int prop_grid = (NN + 3) / 4;      // 25000

  // Layer 1: V0 | a1 | U2s, then lhat(a1 + 2*lhat(U2s)) via two 1-line rounds
  k_gemm_x<<<gemm_grid, 256, 0, stream>>>(x, BtX, dinv, gV0, gA1, gU2s);
  k_propA<<<prop_grid, 256, 0, stream>>>(rowptr, adj, gU2s, gA1, dinv, gM1);
  k_propB<<<prop_grid, 256, 0, stream>>>(rowptr, adj, gM1, gV0, b1v, dinv, gH1);
  // Layer 2: V02 | a2 | b2s, then two 1-line rounds; h2 table + separate pool
  k_gemm_h<<<gemm_grid, 256, 0, stream>>>(gH1, BtH2, dinv, gV02, gA2, gB2s);
  k_propA<<<prop_grid, 256, 0, stream>>>(rowptr, adj, gB2s, gA2, dinv, gM2);
  k_propD<<<prop_grid, 256, 0, stream>>>(rowptr, adj, gM2, gV02, b2v, dinv, gH2);
  k_pool<<<NBK, 256, 0, stream>>>(gH2, b32, pooled);
  k_out<<<NG, 64, 0, stream>>>(pooled, gcnt, Wfc, bfc, out);
}